// Round 3
// baseline (230.116 us; speedup 1.0000x reference)
//
#include <hip/hip_runtime.h>

#define THREADS 256
#define ROWS 2  // 4096 blocks: 8 resident/CU + continuous backfill re-staggering

typedef float f4 __attribute__((ext_vector_type(4)));

// LDS-only barrier: waits ds ops (lgkmcnt) but lets global loads/stores stay
// in flight across the barrier (T4: never vmcnt(0) in the main loop).
#define BARRIER_LDS() asm volatile("s_waitcnt lgkmcnt(0)\ns_barrier" ::: "memory")

// Radix-4 in-place unnormalized WHT on 4 values.
__device__ __forceinline__ void fwht4(float& a, float& b, float& c, float& d) {
  float s0 = a + b, d0 = a - b, s1 = c + d, d1 = c - d;
  a = s0 + s1; b = d0 + d1; c = s0 - s1; d = d0 - d1;
}

// 16-point in-place WHT over v[0..15] (H16 = H4 (x) H4, order-independent).
__device__ __forceinline__ void fwht16(float v[16]) {
#pragma unroll
  for (int j = 0; j < 4; ++j) fwht4(v[j * 4 + 0], v[j * 4 + 1], v[j * 4 + 2], v[j * 4 + 3]);
#pragma unroll
  for (int j = 0; j < 4; ++j) fwht4(v[0 + j], v[4 + j], v[8 + j], v[12 + j]);
}

// LDS swizzle: logical word i -> i + 4*(i>>6). All transpose access patterns
// are <=2-way bank-aliased (free on gfx950, m136), and any 16B-aligned run of
// 4 words within a 64-block stays contiguous (ds_*_b128 legal).
__device__ __forceinline__ int pad(int i) { return i + ((i >> 6) << 2); }

__global__ __launch_bounds__(THREADS, 8) void hadamard4096_kernel(
    const float* __restrict__ in, float* __restrict__ out, int nrows) {
  // 4096 data words + 4 pad words per 64 -> 17408 B; 8 blocks/CU = 139 KB LDS.
  __shared__ __align__(16) float lds[4096 + 256];

  const int t = threadIdx.x;
  const int kk = t >> 6;
  const int ss = (t >> 2) & 15;
  const int jj = t & 3;
  // pad-folded LDS bases (verified index math — unchanged).
  const int a1base = kk * 1024 + ss * 64 + jj + 4 * (kk * 16 + ss);
  const int a2base = kk * 1088 + 4 * ss + jj;

  const int row0 = blockIdx.x * ROWS;
  const f4* in4 = reinterpret_cast<const f4*>(in) + (size_t)row0 * 1024 + t;
  float* op = out + (size_t)row0 * 4096 + kk * 1024 + (t & 63);

  // Prologue: issue row0's 4 dwordx4 loads. PLAIN loads: both measured
  // near-ceiling baselines (fill 6.65 TB/s, m13 copy 6.29 TB/s) use plain
  // L2-allocating accesses; NT bypass is unproven on this chip and was never
  // isolated from the R1 pipeline change.
  f4 b0 = in4[0 * 256];
  f4 b1 = in4[1 * 256];
  f4 b2 = in4[2 * 256];
  f4 b3 = in4[3 * 256];

#pragma unroll
  for (int r = 0; r < ROWS; ++r) {
    if (row0 + r >= nrows) break;  // block-uniform (barrier-safe)

    // ---- Phase-1a: consume staging regs (counted vmcnt on exactly these 4
    //      loads; prior stores stay outstanding). Radix-4 over bits {1:0}.
    float v[16];
    v[0] = b0.x; v[1] = b0.y; v[2] = b0.z; v[3] = b0.w;
    fwht4(v[0], v[1], v[2], v[3]);
    v[4] = b1.x; v[5] = b1.y; v[6] = b1.z; v[7] = b1.w;
    fwht4(v[4], v[5], v[6], v[7]);
    v[8] = b2.x; v[9] = b2.y; v[10] = b2.z; v[11] = b2.w;
    fwht4(v[8], v[9], v[10], v[11]);
    v[12] = b3.x; v[13] = b3.y; v[14] = b3.z; v[15] = b3.w;
    fwht4(v[12], v[13], v[14], v[15]);

    // ---- Prefetch next row: stays in flight across the lgkmcnt-only
    //      barriers; consumed only at next iteration's phase-1a.
    if (r + 1 < ROWS && row0 + r + 1 < nrows) {
      const f4* nx = in4 + (size_t)(r + 1) * 1024;
      b0 = nx[0 * 256];
      b1 = nx[1 * 256];
      b2 = nx[2 * 256];
      b3 = nx[3 * 256];
    }

    // ---- Phase-1b: radix-4 over bits {11:10} (the register dimension).
#pragma unroll
    for (int j = 0; j < 4; ++j) fwht4(v[0 + j], v[4 + j], v[8 + j], v[12 + j]);

    // WAR barrier (rows 1..): prev row's T2-reads must precede this T1-write.
    if (r) BARRIER_LDS();

    // ---- Transpose-1 write: contiguous 4-word groups -> ds_write_b128.
#pragma unroll
    for (int c = 0; c < 4; ++c) {
      f4 w = {v[c * 4 + 0], v[c * 4 + 1], v[c * 4 + 2], v[c * 4 + 3]};
      *reinterpret_cast<f4*>(&lds[pad(c * 1024 + 4 * t)]) = w;
    }
    BARRIER_LDS();

    // ---- Transpose-1 read: thread (kk,ss,jj) gathers q=0..15 at
    //      idx = kk*1024 + ss*64 + 4q + jj; padded base + 16B offsets.
#pragma unroll
    for (int q = 0; q < 16; ++q) v[q] = lds[a1base + 4 * q];

    // ---- Phase 2: H16 over element bits {5:2}
    fwht16(v);

    // ---- Transpose-2 write: self-owned addresses (same as just read).
#pragma unroll
    for (int q = 0; q < 16; ++q) lds[a1base + 4 * q] = v[q];
    BARRIER_LDS();

    // ---- Transpose-2 read: thread (kk,qq,jj) gathers s=0..15 at
    //      idx = kk*1024 + 64s + 4qq + jj; padded stride = 68 words.
#pragma unroll
    for (int s = 0; s < 16; ++s) v[s] = lds[a2base + 68 * s];

    // ---- Phase 3: H16 over element bits {9:6}, scaled by 1/sqrt(4096).
    fwht16(v);

    // ---- Store: per s, lanes cover 256 contiguous bytes (coalesced dwords).
    //      PLAIN stores: let L2 write-combine full lines (fill-kernel path).
    float* o = op + (size_t)r * 4096;
#pragma unroll
    for (int s = 0; s < 16; ++s) o[64 * s] = v[s] * 0.015625f;
  }
}

extern "C" void kernel_launch(void* const* d_in, const int* in_sizes, int n_in,
                              void* d_out, int out_size, void* d_ws, size_t ws_size,
                              hipStream_t stream) {
  const float* x = (const float*)d_in[0];
  float* out = (float*)d_out;
  const int rows = in_sizes[0] >> 12;  // 8192 rows of 4096
  const int blocks = (rows + ROWS - 1) / ROWS;
  hipLaunchKernelGGL(hadamard4096_kernel, dim3(blocks), dim3(THREADS), 0, stream,
                     x, out, rows);
}

// Round 4
// 217.474 us; speedup vs baseline: 1.0581x; 1.0581x over previous
//
#include <hip/hip_runtime.h>

#define THREADS 256
#define ROWS 2  // 4096 blocks: 8 resident/CU + continuous backfill re-staggering

typedef float f4 __attribute__((ext_vector_type(4)));

// LDS-only barrier: waits ds ops (lgkmcnt) but lets global loads/stores stay
// in flight across the barrier. Critical with NT stores: they complete at HBM
// latency (no L2 absorption), so __syncthreads()'s vmcnt(0) drain would expose
// the full store round-trip at every barrier (3x per row).
#define BARRIER_LDS() asm volatile("s_waitcnt lgkmcnt(0)\ns_barrier" ::: "memory")

// Radix-4 in-place unnormalized WHT on 4 values.
__device__ __forceinline__ void fwht4(float& a, float& b, float& c, float& d) {
  float s0 = a + b, d0 = a - b, s1 = c + d, d1 = c - d;
  a = s0 + s1; b = d0 + d1; c = s0 - s1; d = d0 - d1;
}

// 16-point in-place WHT over v[0..15] (H16 = H4 (x) H4, order-independent).
__device__ __forceinline__ void fwht16(float v[16]) {
#pragma unroll
  for (int j = 0; j < 4; ++j) fwht4(v[j * 4 + 0], v[j * 4 + 1], v[j * 4 + 2], v[j * 4 + 3]);
#pragma unroll
  for (int j = 0; j < 4; ++j) fwht4(v[0 + j], v[4 + j], v[8 + j], v[12 + j]);
}

// LDS swizzle: logical word i -> i + 4*(i>>6). All transpose access patterns
// are <=2-way bank-aliased (free on gfx950, m136), and any 16B-aligned run of
// 4 words within a 64-block stays contiguous (ds_*_b128 legal).
__device__ __forceinline__ int pad(int i) { return i + ((i >> 6) << 2); }

__global__ __launch_bounds__(THREADS, 8) void hadamard4096_kernel(
    const float* __restrict__ in, float* __restrict__ out, int nrows) {
  // 4096 data words + 4 pad words per 64 -> 17408 B; 8 blocks/CU = 139 KB LDS.
  __shared__ __align__(16) float lds[4096 + 256];

  const int t = threadIdx.x;
  const int kk = t >> 6;
  const int ss = (t >> 2) & 15;
  const int jj = t & 3;
  // pad-folded LDS bases (verified index math — unchanged).
  const int a1base = kk * 1024 + ss * 64 + jj + 4 * (kk * 16 + ss);
  const int a2base = kk * 1088 + 4 * ss + jj;

  const int row0 = blockIdx.x * ROWS;
  const f4* in4 = reinterpret_cast<const f4*>(in) + (size_t)row0 * 1024 + t;
  float* op = out + (size_t)row0 * 4096 + kk * 1024 + (t & 63);

  // Prologue: row0's 4 dwordx4 loads. NONTEMPORAL is the proven lever (R1 vs
  // R0/R3, +~12us): in+out = 268 MB > 256 MB L3, so plain accesses thrash L3
  // with touch-once lines; NT streams past the cache.
  f4 b0 = __builtin_nontemporal_load(in4 + 0 * 256);
  f4 b1 = __builtin_nontemporal_load(in4 + 1 * 256);
  f4 b2 = __builtin_nontemporal_load(in4 + 2 * 256);
  f4 b3 = __builtin_nontemporal_load(in4 + 3 * 256);

#pragma unroll
  for (int r = 0; r < ROWS; ++r) {
    if (row0 + r >= nrows) break;  // block-uniform (barrier-safe)

    // ---- Phase-1a: consume staging regs (counted vmcnt on exactly these 4
    //      loads; prior stores stay outstanding). Radix-4 over bits {1:0}.
    float v[16];
    v[0] = b0.x; v[1] = b0.y; v[2] = b0.z; v[3] = b0.w;
    fwht4(v[0], v[1], v[2], v[3]);
    v[4] = b1.x; v[5] = b1.y; v[6] = b1.z; v[7] = b1.w;
    fwht4(v[4], v[5], v[6], v[7]);
    v[8] = b2.x; v[9] = b2.y; v[10] = b2.z; v[11] = b2.w;
    fwht4(v[8], v[9], v[10], v[11]);
    v[12] = b3.x; v[13] = b3.y; v[14] = b3.z; v[15] = b3.w;
    fwht4(v[12], v[13], v[14], v[15]);

    // ---- Prefetch next row: stays in flight across the lgkmcnt-only
    //      barriers; consumed only at next iteration's phase-1a.
    if (r + 1 < ROWS && row0 + r + 1 < nrows) {
      const f4* nx = in4 + (size_t)(r + 1) * 1024;
      b0 = __builtin_nontemporal_load(nx + 0 * 256);
      b1 = __builtin_nontemporal_load(nx + 1 * 256);
      b2 = __builtin_nontemporal_load(nx + 2 * 256);
      b3 = __builtin_nontemporal_load(nx + 3 * 256);
    }

    // ---- Phase-1b: radix-4 over bits {11:10} (the register dimension).
#pragma unroll
    for (int j = 0; j < 4; ++j) fwht4(v[0 + j], v[4 + j], v[8 + j], v[12 + j]);

    // WAR barrier (rows 1..): prev row's T2-reads must precede this T1-write.
    if (r) BARRIER_LDS();

    // ---- Transpose-1 write: contiguous 4-word groups -> ds_write_b128.
#pragma unroll
    for (int c = 0; c < 4; ++c) {
      f4 w = {v[c * 4 + 0], v[c * 4 + 1], v[c * 4 + 2], v[c * 4 + 3]};
      *reinterpret_cast<f4*>(&lds[pad(c * 1024 + 4 * t)]) = w;
    }
    BARRIER_LDS();

    // ---- Transpose-1 read: thread (kk,ss,jj) gathers q=0..15 at
    //      idx = kk*1024 + ss*64 + 4q + jj; padded base + 16B offsets.
#pragma unroll
    for (int q = 0; q < 16; ++q) v[q] = lds[a1base + 4 * q];

    // ---- Phase 2: H16 over element bits {5:2}
    fwht16(v);

    // ---- Transpose-2 write: self-owned addresses (same as just read).
#pragma unroll
    for (int q = 0; q < 16; ++q) lds[a1base + 4 * q] = v[q];
    BARRIER_LDS();

    // ---- Transpose-2 read: thread (kk,qq,jj) gathers s=0..15 at
    //      idx = kk*1024 + 64s + 4qq + jj; padded stride = 68 words.
#pragma unroll
    for (int s = 0; s < 16; ++s) v[s] = lds[a2base + 68 * s];

    // ---- Phase 3: H16 over element bits {9:6}, scaled by 1/sqrt(4096).
    fwht16(v);

    // ---- Store: per s, lanes cover 256 contiguous bytes (coalesced dwords).
    //      NT fire-and-forget; never drained inside the loop (lgkm barriers).
    float* o = op + (size_t)r * 4096;
#pragma unroll
    for (int s = 0; s < 16; ++s)
      __builtin_nontemporal_store(v[s] * 0.015625f, o + 64 * s);
  }
}

extern "C" void kernel_launch(void* const* d_in, const int* in_sizes, int n_in,
                              void* d_out, int out_size, void* d_ws, size_t ws_size,
                              hipStream_t stream) {
  const float* x = (const float*)d_in[0];
  float* out = (float*)d_out;
  const int rows = in_sizes[0] >> 12;  // 8192 rows of 4096
  const int blocks = (rows + ROWS - 1) / ROWS;
  hipLaunchKernelGGL(hadamard4096_kernel, dim3(blocks), dim3(THREADS), 0, stream,
                     x, out, rows);
}